// Round 6
// baseline (289.976 us; speedup 1.0000x reference)
//
#include <hip/hip_runtime.h>
#include <math.h>

// Problem dims (fixed by reference):
#define B_DIM 8
#define F_DIM 128
#define T_DIM 16384

#define THREADS 512
#define CHUNK  (T_DIM / THREADS)   // 32 elements per thread
#define CHUNK4 (CHUNK / 4)         // 8 float4 per thread
#define LOG2_CHUNK 5

#define BATCHES_PER_BLOCK 2
#define BLOCKS_PER_F (B_DIM / BATCHES_PER_BLOCK)   // 4
#define GRID (F_DIM * BLOCKS_PER_F)                // 512 blocks

typedef float f32x4 __attribute__((ext_vector_type(4)));

// ---------------------------------------------------------------------------
// Fused PCEN kernel.
// Each block: (1) parallel EMA scan of row f of data[0] (affine composition:
// m_t = a*m_{t-1} + s*x_t, segments compose as m_out = A*m_in + B), keeping
// this thread's 32 m-values in registers; (2) Mepow = sign(m+eps)*|m+eps|^alpha
// and rc = 1/Mepow in registers (never touches memory); (3) apply to
// BATCHES_PER_BLOCK batches: out = sqrt(data*rc + delta) - sqrt(delta).
//
// Mapping: f = bid & 127, sub = bid >> 7. The BLOCKS_PER_F blocks sharing a
// row are 128 apart -> same XCD (128 % 8 == 0) -> redundant scan reads hit L2.
// 512 blocks x 512 threads = 2 blocks/CU (launch_bounds caps VGPR at 128).
// ---------------------------------------------------------------------------
__global__ __launch_bounds__(THREADS, 4) void pcen_fused_kernel(
    const float* __restrict__ data,    // [B, F, T]
    const float* __restrict__ p_alpha,
    const float* __restrict__ p_r,
    const float* __restrict__ p_delta,
    const float* __restrict__ p_s,
    const float* __restrict__ p_eps,
    float* __restrict__ out)           // [B, F, T]
{
    const float alpha = p_alpha[0];
    const float s     = p_s[0];
    const float eps   = p_eps[0];
    const float a     = 1.0f - s;
    const float r_abs = fabsf(p_r[0]);
    const float delta = p_delta[0];

    const int bid  = blockIdx.x;
    const int f    = bid & (F_DIM - 1);
    const int sub  = bid >> 7;               // 0..BLOCKS_PER_F-1
    const int tid  = threadIdx.x;
    const int lane = tid & 63;
    const int wave = tid >> 6;

    const f32x4* xrow = (const f32x4*)(data + (size_t)f * T_DIM);
    const int vbase = tid * CHUNK4;

    // ---- Phase A: local recurrence with zero init; keep local m values in regs
    f32x4 y[CHUNK4];
    float m = 0.0f;
#pragma unroll
    for (int j = 0; j < CHUNK4; ++j) {
        f32x4 x = xrow[vbase + j];
        m = fmaf(a, m, s * x.x); x.x = m;
        m = fmaf(a, m, s * x.y); x.y = m;
        m = fmaf(a, m, s * x.z); x.z = m;
        m = fmaf(a, m, s * x.w); x.w = m;
        y[j] = x;
    }

    // Chunk transfer function: A = a^CHUNK (by squaring), B = final local m
    float A = a;
#pragma unroll
    for (int i = 0; i < LOG2_CHUNK; ++i) A = A * A;
    float B = m;

    // ---- Inclusive affine scan across the 64 lanes (Hillis-Steele)
#pragma unroll
    for (int d = 1; d < 64; d <<= 1) {
        float Ap = __shfl_up(A, d);
        float Bp = __shfl_up(B, d);
        if (lane >= d) {
            B = fmaf(A, Bp, B);   // prev segment first, then mine
            A = A * Ap;
        }
    }

    // ---- Cross-wave combine via LDS (8 waves)
    __shared__ float wA[THREADS / 64];
    __shared__ float wB[THREADS / 64];
    if (lane == 63) { wA[wave] = A; wB[wave] = B; }
    __syncthreads();

    // exclusive scan within wave (state entering this thread's chunk, ignoring prior waves)
    float Ae = __shfl_up(A, 1);
    float Be = __shfl_up(B, 1);
    if (lane == 0) { Ae = 1.0f; Be = 0.0f; }

    // carry from all preceding waves applied to initial state 0
    float cB = 0.0f;
    for (int w = 0; w < wave; ++w) cB = fmaf(wA[w], cB, wB[w]);

    // true state entering this thread's chunk
    const float m_in = fmaf(Ae, cB, Be);

    // ---- Phase B: fixup m_k = y_k + a^(k+1)*m_in, Mepow via v_log/v_exp,
    // then rc = 1/Mepow, all in registers (y[] repurposed as rc).
    float ap = a;
#pragma unroll
    for (int j = 0; j < CHUNK4; ++j) {
        f32x4 yv = y[j];
        f32x4 me;
        {
            float mv = fmaf(ap, m_in, yv.x); ap *= a;
            float mad = mv + eps;
            me.x = copysignf(__builtin_amdgcn_exp2f(alpha * __builtin_amdgcn_logf(fabsf(mad))), mad);
        }
        {
            float mv = fmaf(ap, m_in, yv.y); ap *= a;
            float mad = mv + eps;
            me.y = copysignf(__builtin_amdgcn_exp2f(alpha * __builtin_amdgcn_logf(fabsf(mad))), mad);
        }
        {
            float mv = fmaf(ap, m_in, yv.z); ap *= a;
            float mad = mv + eps;
            me.z = copysignf(__builtin_amdgcn_exp2f(alpha * __builtin_amdgcn_logf(fabsf(mad))), mad);
        }
        {
            float mv = fmaf(ap, m_in, yv.w); ap *= a;
            float mad = mv + eps;
            me.w = copysignf(__builtin_amdgcn_exp2f(alpha * __builtin_amdgcn_logf(fabsf(mad))), mad);
        }
        f32x4 rc;
        rc.x = 1.0f / me.x;
        rc.y = 1.0f / me.y;
        rc.z = 1.0f / me.z;
        rc.w = 1.0f / me.w;
        y[j] = rc;
    }

    // ---- Phase C: apply to this block's batches; data/out are streaming -> NT.
    const size_t row_off = (size_t)f * T_DIM;
    const int b0 = sub * BATCHES_PER_BLOCK;

    if (r_abs == 0.5f) {
        const float dpr = sqrtf(delta);
#pragma unroll
        for (int bb = 0; bb < BATCHES_PER_BLOCK; ++bb) {
            const int b = b0 + bb;
            const f32x4* __restrict__ d4 = (const f32x4*)(data + (size_t)b * F_DIM * T_DIM + row_off) + vbase;
            f32x4* __restrict__       o4 = (f32x4*)(out + (size_t)b * F_DIM * T_DIM + row_off) + vbase;
#pragma unroll
            for (int j = 0; j < CHUNK4; ++j) {
                f32x4 x = __builtin_nontemporal_load(d4 + j);
                f32x4 rc = y[j];
                f32x4 o;
                o.x = sqrtf(fmaf(x.x, rc.x, delta)) - dpr;
                o.y = sqrtf(fmaf(x.y, rc.y, delta)) - dpr;
                o.z = sqrtf(fmaf(x.z, rc.z, delta)) - dpr;
                o.w = sqrtf(fmaf(x.w, rc.w, delta)) - dpr;
                __builtin_nontemporal_store(o, o4 + j);
            }
        }
    } else {
        const float dpr = powf(delta, r_abs);
#pragma unroll
        for (int bb = 0; bb < BATCHES_PER_BLOCK; ++bb) {
            const int b = b0 + bb;
            const f32x4* __restrict__ d4 = (const f32x4*)(data + (size_t)b * F_DIM * T_DIM + row_off) + vbase;
            f32x4* __restrict__       o4 = (f32x4*)(out + (size_t)b * F_DIM * T_DIM + row_off) + vbase;
#pragma unroll
            for (int j = 0; j < CHUNK4; ++j) {
                f32x4 x = __builtin_nontemporal_load(d4 + j);
                f32x4 rc = y[j];
                f32x4 o;
                o.x = powf(fmaf(x.x, rc.x, delta), r_abs) - dpr;
                o.y = powf(fmaf(x.y, rc.y, delta), r_abs) - dpr;
                o.z = powf(fmaf(x.z, rc.z, delta), r_abs) - dpr;
                o.w = powf(fmaf(x.w, rc.w, delta), r_abs) - dpr;
                __builtin_nontemporal_store(o, o4 + j);
            }
        }
    }
}

// ---------------------------------------------------------------------------
extern "C" void kernel_launch(void* const* d_in, const int* in_sizes, int n_in,
                              void* d_out, int out_size, void* d_ws, size_t ws_size,
                              hipStream_t stream) {
    const float* data    = (const float*)d_in[0];
    const float* p_alpha = (const float*)d_in[1];
    const float* p_r     = (const float*)d_in[2];
    const float* p_delta = (const float*)d_in[3];
    const float* p_s     = (const float*)d_in[4];
    const float* p_eps   = (const float*)d_in[5];
    float* out = (float*)d_out;

    pcen_fused_kernel<<<GRID, THREADS, 0, stream>>>(
        data, p_alpha, p_r, p_delta, p_s, p_eps, out);
}

// Round 12
// 130.401 us; speedup vs baseline: 2.2237x; 2.2237x over previous
//
#include <hip/hip_runtime.h>
#include <math.h>

// Problem dims (fixed by reference):
#define B_DIM 8
#define F_DIM 128
#define T_DIM 16384

#define THREADS 512
#define CHUNK  (T_DIM / THREADS)   // 32 elements per thread
#define CHUNK4 (CHUNK / 4)         // 8 float4 per thread
#define LOG2_CHUNK 5

#define ROW4 (T_DIM / 4)           // 4096 float4 per row
#define BATCHES_PER_BLOCK 2
#define BLOCKS_PER_F (B_DIM / BATCHES_PER_BLOCK)   // 4
#define GRID (F_DIM * BLOCKS_PER_F)                // 512 blocks

typedef float f32x4 __attribute__((ext_vector_type(4)));

// ---------------------------------------------------------------------------
// Fused PCEN kernel, layout-swapped through LDS.
//
// Scan needs chunk-per-thread (sequential recurrence); apply needs
// lane-contiguous (coalesced HBM). A 64 KB LDS row buffer with XOR swizzle
//   slot(v) = v ^ ((v>>3)&7)        (v = float4 index within row)
// makes all four access patterns conflict-free b128 (8 words/bank):
//   1. coalesced write of x      (v = j*512+tid)
//   2. chunk read of x           (v = tid*8+c)
//   3. chunk write of rc         (v = tid*8+c)
//   4. coalesced read of rc      (v = j*512+tid)
//
// Mapping: f = bid&127, sub = bid>>7; the 4 blocks sharing a row are 128
// apart -> same XCD -> redundant scan reads hit that XCD's L2.
// ---------------------------------------------------------------------------
__global__ __launch_bounds__(THREADS, 4) void pcen_fused_kernel(
    const float* __restrict__ data,    // [B, F, T]
    const float* __restrict__ p_alpha,
    const float* __restrict__ p_r,
    const float* __restrict__ p_delta,
    const float* __restrict__ p_s,
    const float* __restrict__ p_eps,
    float* __restrict__ out)           // [B, F, T]
{
    const float alpha = p_alpha[0];
    const float s     = p_s[0];
    const float eps   = p_eps[0];
    const float a     = 1.0f - s;
    const float r_abs = fabsf(p_r[0]);
    const float delta = p_delta[0];

    const int bid  = blockIdx.x;
    const int f    = bid & (F_DIM - 1);
    const int sub  = bid >> 7;               // 0..3
    const int tid  = threadIdx.x;
    const int lane = tid & 63;
    const int wave = tid >> 6;
    const int sw   = (tid >> 3) & 7;         // swizzle for coalesced-indexed ops
    const int tlow = tid & 7;                // swizzle for chunk-indexed ops

    __shared__ f32x4 lds4[ROW4];             // 64 KB row buffer (x, then rc)
    __shared__ float wA[THREADS / 64];
    __shared__ float wB[THREADS / 64];

    // ---- Phase 1: coalesced load of row f of data[0] into LDS (swizzled).
    // Normal (cached) loads: 4 replica blocks on the same XCD share via L2.
    const f32x4* __restrict__ xrow4 = (const f32x4*)(data + (size_t)f * T_DIM);
#pragma unroll
    for (int j = 0; j < CHUNK4; ++j) {
        const int v = j * THREADS + tid;
        lds4[v ^ sw] = xrow4[v];
    }
    __syncthreads();

    // ---- Phase 2: chunk read from LDS, local recurrence (zero init).
    const int cbase = tid * CHUNK4;
    f32x4 y[CHUNK4];
    float m = 0.0f;
#pragma unroll
    for (int c = 0; c < CHUNK4; ++c) {
        f32x4 x = lds4[cbase + (c ^ tlow)];
        m = fmaf(a, m, s * x.x); x.x = m;
        m = fmaf(a, m, s * x.y); x.y = m;
        m = fmaf(a, m, s * x.z); x.z = m;
        m = fmaf(a, m, s * x.w); x.w = m;
        y[c] = x;
    }

    // Chunk transfer function: A = a^CHUNK (by squaring), B = final local m
    float A = a;
#pragma unroll
    for (int i = 0; i < LOG2_CHUNK; ++i) A = A * A;
    float B = m;

    // ---- Inclusive affine scan across the 64 lanes (Hillis-Steele)
#pragma unroll
    for (int d = 1; d < 64; d <<= 1) {
        float Ap = __shfl_up(A, d);
        float Bp = __shfl_up(B, d);
        if (lane >= d) {
            B = fmaf(A, Bp, B);   // prev segment first, then mine
            A = A * Ap;
        }
    }

    // ---- Cross-wave combine (8 waves)
    if (lane == 63) { wA[wave] = A; wB[wave] = B; }
    __syncthreads();   // also guarantees all phase-2 LDS reads completed

    float Ae = __shfl_up(A, 1);
    float Be = __shfl_up(B, 1);
    if (lane == 0) { Ae = 1.0f; Be = 0.0f; }

    float cB = 0.0f;
    for (int w = 0; w < wave; ++w) cB = fmaf(wA[w], cB, wB[w]);

    const float m_in = fmaf(Ae, cB, Be);     // state entering this chunk

    // ---- Phase 3: fixup m_k = y_k + a^(k+1)*m_in, Mepow via v_log/v_exp,
    // rc = 1/Mepow, write back to LDS (overwrites x region — safe post-barrier).
    float ap = a;
#pragma unroll
    for (int c = 0; c < CHUNK4; ++c) {
        f32x4 yv = y[c];
        f32x4 rc;
        {
            float mv = fmaf(ap, m_in, yv.x); ap *= a;
            float mad = mv + eps;
            rc.x = 1.0f / copysignf(__builtin_amdgcn_exp2f(alpha * __builtin_amdgcn_logf(fabsf(mad))), mad);
        }
        {
            float mv = fmaf(ap, m_in, yv.y); ap *= a;
            float mad = mv + eps;
            rc.y = 1.0f / copysignf(__builtin_amdgcn_exp2f(alpha * __builtin_amdgcn_logf(fabsf(mad))), mad);
        }
        {
            float mv = fmaf(ap, m_in, yv.z); ap *= a;
            float mad = mv + eps;
            rc.z = 1.0f / copysignf(__builtin_amdgcn_exp2f(alpha * __builtin_amdgcn_logf(fabsf(mad))), mad);
        }
        {
            float mv = fmaf(ap, m_in, yv.w); ap *= a;
            float mad = mv + eps;
            rc.w = 1.0f / copysignf(__builtin_amdgcn_exp2f(alpha * __builtin_amdgcn_logf(fabsf(mad))), mad);
        }
        lds4[cbase + (c ^ tlow)] = rc;
    }
    __syncthreads();

    // ---- Phase 4: hoist rc (coalesced-indexed, swizzled) into registers,
    // then apply to this block's batches with fully coalesced NT global I/O.
    f32x4 rcj[CHUNK4];
#pragma unroll
    for (int j = 0; j < CHUNK4; ++j) {
        rcj[j] = lds4[(j * THREADS + tid) ^ sw];
    }

    const size_t row_off = (size_t)f * T_DIM;
    const int b0 = sub * BATCHES_PER_BLOCK;

    if (r_abs == 0.5f) {
        const float dpr = sqrtf(delta);
#pragma unroll
        for (int bb = 0; bb < BATCHES_PER_BLOCK; ++bb) {
            const int b = b0 + bb;
            const f32x4* __restrict__ d4 = (const f32x4*)(data + (size_t)b * F_DIM * T_DIM + row_off);
            f32x4* __restrict__       o4 = (f32x4*)(out + (size_t)b * F_DIM * T_DIM + row_off);
#pragma unroll
            for (int j = 0; j < CHUNK4; ++j) {
                const int v = j * THREADS + tid;
                f32x4 x = __builtin_nontemporal_load(d4 + v);
                f32x4 rc = rcj[j];
                f32x4 o;
                o.x = sqrtf(fmaf(x.x, rc.x, delta)) - dpr;
                o.y = sqrtf(fmaf(x.y, rc.y, delta)) - dpr;
                o.z = sqrtf(fmaf(x.z, rc.z, delta)) - dpr;
                o.w = sqrtf(fmaf(x.w, rc.w, delta)) - dpr;
                __builtin_nontemporal_store(o, o4 + v);
            }
        }
    } else {
        const float dpr = powf(delta, r_abs);
#pragma unroll
        for (int bb = 0; bb < BATCHES_PER_BLOCK; ++bb) {
            const int b = b0 + bb;
            const f32x4* __restrict__ d4 = (const f32x4*)(data + (size_t)b * F_DIM * T_DIM + row_off);
            f32x4* __restrict__       o4 = (f32x4*)(out + (size_t)b * F_DIM * T_DIM + row_off);
#pragma unroll
            for (int j = 0; j < CHUNK4; ++j) {
                const int v = j * THREADS + tid;
                f32x4 x = __builtin_nontemporal_load(d4 + v);
                f32x4 rc = rcj[j];
                f32x4 o;
                o.x = powf(fmaf(x.x, rc.x, delta), r_abs) - dpr;
                o.y = powf(fmaf(x.y, rc.y, delta), r_abs) - dpr;
                o.z = powf(fmaf(x.z, rc.z, delta), r_abs) - dpr;
                o.w = powf(fmaf(x.w, rc.w, delta), r_abs) - dpr;
                __builtin_nontemporal_store(o, o4 + v);
            }
        }
    }
}

// ---------------------------------------------------------------------------
extern "C" void kernel_launch(void* const* d_in, const int* in_sizes, int n_in,
                              void* d_out, int out_size, void* d_ws, size_t ws_size,
                              hipStream_t stream) {
    const float* data    = (const float*)d_in[0];
    const float* p_alpha = (const float*)d_in[1];
    const float* p_r     = (const float*)d_in[2];
    const float* p_delta = (const float*)d_in[3];
    const float* p_s     = (const float*)d_in[4];
    const float* p_eps   = (const float*)d_in[5];
    float* out = (float*)d_out;

    pcen_fused_kernel<<<GRID, THREADS, 0, stream>>>(
        data, p_alpha, p_r, p_delta, p_s, p_eps, out);
}

// Round 13
// 127.888 us; speedup vs baseline: 2.2674x; 1.0197x over previous
//
#include <hip/hip_runtime.h>
#include <math.h>

// Problem dims (fixed by reference):
#define B_DIM 8
#define F_DIM 128
#define T_DIM 16384

#define THREADS 512
#define CHUNK  (T_DIM / THREADS)   // 32 elements per thread
#define CHUNK4 (CHUNK / 4)         // 8 float4 per thread
#define LOG2_CHUNK 5

#define ROW4 (T_DIM / 4)           // 4096 float4 per row
#define BATCHES_PER_BLOCK 2
#define BLOCKS_PER_F (B_DIM / BATCHES_PER_BLOCK)   // 4
#define GRID (F_DIM * BLOCKS_PER_F)                // 512 blocks (= 2/CU, all resident)

typedef float f32x4 __attribute__((ext_vector_type(4)));

// ---------------------------------------------------------------------------
// Fused PCEN kernel, layout-swapped through LDS, with batch-0 prefetch
// overlapped under the scan phase.
//
// LDS XOR swizzle slot(v) = v ^ ((v>>3)&7) keeps all four access patterns
// conflict-free b128 (verified: round-12 SQ_LDS_BANK_CONFLICT = 0).
// Mapping: f = bid&127, sub = bid>>7; replica blocks 128 apart -> same XCD.
// ---------------------------------------------------------------------------
__global__ __launch_bounds__(THREADS, 4) void pcen_fused_kernel(
    const float* __restrict__ data,    // [B, F, T]
    const float* __restrict__ p_alpha,
    const float* __restrict__ p_r,
    const float* __restrict__ p_delta,
    const float* __restrict__ p_s,
    const float* __restrict__ p_eps,
    float* __restrict__ out)           // [B, F, T]
{
    const float alpha = p_alpha[0];
    const float s     = p_s[0];
    const float eps   = p_eps[0];
    const float a     = 1.0f - s;
    const float r_abs = fabsf(p_r[0]);
    const float delta = p_delta[0];

    const int bid  = blockIdx.x;
    const int f    = bid & (F_DIM - 1);
    const int sub  = bid >> 7;               // 0..3
    const int tid  = threadIdx.x;
    const int lane = tid & 63;
    const int wave = tid >> 6;
    const int sw   = (tid >> 3) & 7;         // swizzle for coalesced-indexed ops
    const int tlow = tid & 7;                // swizzle for chunk-indexed ops

    __shared__ f32x4 lds4[ROW4];             // 64 KB row buffer (x, then rc)
    __shared__ float wA[THREADS / 64];
    __shared__ float wB[THREADS / 64];

    const size_t row_off = (size_t)f * T_DIM;
    const int b0 = sub * BATCHES_PER_BLOCK;

    // ---- Phase 0: issue row-f loads (cached — replicas share via L2) ...
    const f32x4* __restrict__ xrow4 = (const f32x4*)(data + row_off);
    f32x4 xs[CHUNK4];
#pragma unroll
    for (int j = 0; j < CHUNK4; ++j) {
        xs[j] = xrow4[j * THREADS + tid];
    }

    // ... then immediately issue batch-b0 prefetch (NT) so its HBM latency
    // hides under the scan/recurrence/transcendental phase.
    const f32x4* __restrict__ d4_0 = (const f32x4*)(data + (size_t)b0 * F_DIM * T_DIM + row_off);
    f32x4 pf[CHUNK4];
#pragma unroll
    for (int j = 0; j < CHUNK4; ++j) {
        pf[j] = __builtin_nontemporal_load(d4_0 + j * THREADS + tid);
    }

    // ---- Phase 1: stage row into LDS (swizzled).
#pragma unroll
    for (int j = 0; j < CHUNK4; ++j) {
        lds4[(j * THREADS + tid) ^ sw] = xs[j];
    }
    __syncthreads();

    // ---- Phase 2: chunk read from LDS, local recurrence (zero init).
    const int cbase = tid * CHUNK4;
    f32x4 y[CHUNK4];
    float m = 0.0f;
#pragma unroll
    for (int c = 0; c < CHUNK4; ++c) {
        f32x4 x = lds4[cbase + (c ^ tlow)];
        m = fmaf(a, m, s * x.x); x.x = m;
        m = fmaf(a, m, s * x.y); x.y = m;
        m = fmaf(a, m, s * x.z); x.z = m;
        m = fmaf(a, m, s * x.w); x.w = m;
        y[c] = x;
    }

    // Chunk transfer function: A = a^CHUNK (by squaring), B = final local m
    float A = a;
#pragma unroll
    for (int i = 0; i < LOG2_CHUNK; ++i) A = A * A;
    float B = m;

    // ---- Inclusive affine scan across the 64 lanes (Hillis-Steele)
#pragma unroll
    for (int d = 1; d < 64; d <<= 1) {
        float Ap = __shfl_up(A, d);
        float Bp = __shfl_up(B, d);
        if (lane >= d) {
            B = fmaf(A, Bp, B);   // prev segment first, then mine
            A = A * Ap;
        }
    }

    // ---- Cross-wave combine (8 waves)
    if (lane == 63) { wA[wave] = A; wB[wave] = B; }
    __syncthreads();   // also guarantees all phase-2 LDS reads completed

    float Ae = __shfl_up(A, 1);
    float Be = __shfl_up(B, 1);
    if (lane == 0) { Ae = 1.0f; Be = 0.0f; }

    float cB = 0.0f;
    for (int w = 0; w < wave; ++w) cB = fmaf(wA[w], cB, wB[w]);

    const float m_in = fmaf(Ae, cB, Be);     // state entering this chunk

    // ---- Phase 3: fixup m_k = y_k + a^(k+1)*m_in, Mepow via v_log/v_exp,
    // rc = 1/Mepow, write back to LDS (overwrites x region — safe post-barrier).
    float ap = a;
#pragma unroll
    for (int c = 0; c < CHUNK4; ++c) {
        f32x4 yv = y[c];
        f32x4 rc;
        {
            float mv = fmaf(ap, m_in, yv.x); ap *= a;
            float mad = mv + eps;
            rc.x = 1.0f / copysignf(__builtin_amdgcn_exp2f(alpha * __builtin_amdgcn_logf(fabsf(mad))), mad);
        }
        {
            float mv = fmaf(ap, m_in, yv.y); ap *= a;
            float mad = mv + eps;
            rc.y = 1.0f / copysignf(__builtin_amdgcn_exp2f(alpha * __builtin_amdgcn_logf(fabsf(mad))), mad);
        }
        {
            float mv = fmaf(ap, m_in, yv.z); ap *= a;
            float mad = mv + eps;
            rc.z = 1.0f / copysignf(__builtin_amdgcn_exp2f(alpha * __builtin_amdgcn_logf(fabsf(mad))), mad);
        }
        {
            float mv = fmaf(ap, m_in, yv.w); ap *= a;
            float mad = mv + eps;
            rc.w = 1.0f / copysignf(__builtin_amdgcn_exp2f(alpha * __builtin_amdgcn_logf(fabsf(mad))), mad);
        }
        lds4[cbase + (c ^ tlow)] = rc;
    }
    __syncthreads();

    // ---- Phase 4: hoist rc (coalesced-indexed, swizzled) into registers.
    f32x4 rcj[CHUNK4];
#pragma unroll
    for (int j = 0; j < CHUNK4; ++j) {
        rcj[j] = lds4[(j * THREADS + tid) ^ sw];
    }

    // ---- Phase 5: apply. Batch b0 comes from the prefetch registers;
    // batch b0+1 streams fresh. All global I/O lane-coalesced, NT.
    if (r_abs == 0.5f) {
        const float dpr = sqrtf(delta);
        {
            f32x4* __restrict__ o4 = (f32x4*)(out + (size_t)b0 * F_DIM * T_DIM + row_off);
#pragma unroll
            for (int j = 0; j < CHUNK4; ++j) {
                const int v = j * THREADS + tid;
                f32x4 x = pf[j];
                f32x4 rc = rcj[j];
                f32x4 o;
                o.x = sqrtf(fmaf(x.x, rc.x, delta)) - dpr;
                o.y = sqrtf(fmaf(x.y, rc.y, delta)) - dpr;
                o.z = sqrtf(fmaf(x.z, rc.z, delta)) - dpr;
                o.w = sqrtf(fmaf(x.w, rc.w, delta)) - dpr;
                __builtin_nontemporal_store(o, o4 + v);
            }
        }
        {
            const int b = b0 + 1;
            const f32x4* __restrict__ d4 = (const f32x4*)(data + (size_t)b * F_DIM * T_DIM + row_off);
            f32x4* __restrict__       o4 = (f32x4*)(out + (size_t)b * F_DIM * T_DIM + row_off);
#pragma unroll
            for (int j = 0; j < CHUNK4; ++j) {
                const int v = j * THREADS + tid;
                f32x4 x = __builtin_nontemporal_load(d4 + v);
                f32x4 rc = rcj[j];
                f32x4 o;
                o.x = sqrtf(fmaf(x.x, rc.x, delta)) - dpr;
                o.y = sqrtf(fmaf(x.y, rc.y, delta)) - dpr;
                o.z = sqrtf(fmaf(x.z, rc.z, delta)) - dpr;
                o.w = sqrtf(fmaf(x.w, rc.w, delta)) - dpr;
                __builtin_nontemporal_store(o, o4 + v);
            }
        }
    } else {
        const float dpr = powf(delta, r_abs);
        {
            f32x4* __restrict__ o4 = (f32x4*)(out + (size_t)b0 * F_DIM * T_DIM + row_off);
#pragma unroll
            for (int j = 0; j < CHUNK4; ++j) {
                const int v = j * THREADS + tid;
                f32x4 x = pf[j];
                f32x4 rc = rcj[j];
                f32x4 o;
                o.x = powf(fmaf(x.x, rc.x, delta), r_abs) - dpr;
                o.y = powf(fmaf(x.y, rc.y, delta), r_abs) - dpr;
                o.z = powf(fmaf(x.z, rc.z, delta), r_abs) - dpr;
                o.w = powf(fmaf(x.w, rc.w, delta), r_abs) - dpr;
                __builtin_nontemporal_store(o, o4 + v);
            }
        }
        {
            const int b = b0 + 1;
            const f32x4* __restrict__ d4 = (const f32x4*)(data + (size_t)b * F_DIM * T_DIM + row_off);
            f32x4* __restrict__       o4 = (f32x4*)(out + (size_t)b * F_DIM * T_DIM + row_off);
#pragma unroll
            for (int j = 0; j < CHUNK4; ++j) {
                const int v = j * THREADS + tid;
                f32x4 x = __builtin_nontemporal_load(d4 + v);
                f32x4 rc = rcj[j];
                f32x4 o;
                o.x = powf(fmaf(x.x, rc.x, delta), r_abs) - dpr;
                o.y = powf(fmaf(x.y, rc.y, delta), r_abs) - dpr;
                o.z = powf(fmaf(x.z, rc.z, delta), r_abs) - dpr;
                o.w = powf(fmaf(x.w, rc.w, delta), r_abs) - dpr;
                __builtin_nontemporal_store(o, o4 + v);
            }
        }
    }
}

// ---------------------------------------------------------------------------
extern "C" void kernel_launch(void* const* d_in, const int* in_sizes, int n_in,
                              void* d_out, int out_size, void* d_ws, size_t ws_size,
                              hipStream_t stream) {
    const float* data    = (const float*)d_in[0];
    const float* p_alpha = (const float*)d_in[1];
    const float* p_r     = (const float*)d_in[2];
    const float* p_delta = (const float*)d_in[3];
    const float* p_s     = (const float*)d_in[4];
    const float* p_eps   = (const float*)d_in[5];
    float* out = (float*)d_out;

    pcen_fused_kernel<<<GRID, THREADS, 0, stream>>>(
        data, p_alpha, p_r, p_delta, p_s, p_eps, out);
}